// Round 4
// baseline (457.462 us; speedup 1.0000x reference)
//
#include <hip/hip_runtime.h>
#include <hip/hip_fp16.h>
#include <cstdint>
#include <cstddef>

typedef _Float16 f16x8 __attribute__((ext_vector_type(8)));
typedef _Float16 f16x4 __attribute__((ext_vector_type(4)));
typedef float    f32x4 __attribute__((ext_vector_type(4)));

// ---------------------------------------------------------------------------
// fake-quant with fractional bit-width interpolation (matches jax reference)
// ---------------------------------------------------------------------------
__device__ __forceinline__ float quant_interp(float v, float alpha) {
    float a    = fmaxf(alpha, 1.0f);
    float blo  = floorf(a);
    float frac = a - blo;
    float slo  = exp2f(blo) - 1.0f;
    float shi  = 2.0f * slo + 1.0f;
    float rslo = __builtin_amdgcn_rcpf(slo);
    float rshi = __builtin_amdgcn_rcpf(shi);
    float c    = fminf(fmaxf(v, -1.0f), 1.0f);
    float qlo  = rintf(c * slo) * rslo;
    float qhi  = rintf(c * shi) * rshi;
    return (1.0f - frac) * qlo + frac * qhi;
}

// ---------------------------------------------------------------------------
// column mean of alpha_a [OUT][IN] -> a_feat [IN], deterministic two-pass
// ---------------------------------------------------------------------------
__global__ void colsum_partial_kernel(const float* __restrict__ aA,
                                      float* __restrict__ partial,
                                      int IN, int rows_per) {
    int col = blockIdx.x * blockDim.x + threadIdx.x;
    size_t r0 = (size_t)blockIdx.y * rows_per;
    float s = 0.f;
    for (int r = 0; r < rows_per; ++r)
        s += aA[(r0 + r) * (size_t)IN + col];
    partial[(size_t)blockIdx.y * IN + col] = s;
}

__global__ void colsum_final_kernel(const float* __restrict__ partial,
                                    float* __restrict__ afeat,
                                    int IN, int nchunk, float inv) {
    int col = blockIdx.x * blockDim.x + threadIdx.x;
    float s = 0.f;
    for (int c = 0; c < nchunk; ++c)
        s += partial[(size_t)c * IN + col];
    afeat[col] = s * inv;
}

// ---------------------------------------------------------------------------
// quantize x [M][IN] with per-column alpha -> fp16
// ---------------------------------------------------------------------------
__global__ void quant_x_kernel(const float* __restrict__ x,
                               const float* __restrict__ afeat,
                               f16x4* __restrict__ qx, int IN, size_t n4) {
    size_t i = (size_t)blockIdx.x * blockDim.x + threadIdx.x;
    size_t stride = (size_t)gridDim.x * blockDim.x;
    for (; i < n4; i += stride) {
        size_t e = i * 4;
        int col = (int)(e % (size_t)IN);
        f32x4 xv = *(const f32x4*)(x + e);
        f32x4 av = *(const f32x4*)(afeat + col);
        f16x4 o;
        #pragma unroll
        for (int j = 0; j < 4; ++j) o[j] = (_Float16)quant_interp(xv[j], av[j]);
        qx[i] = o;
    }
}

__global__ void quant_w_kernel(const float* __restrict__ w,
                               const float* __restrict__ aw,
                               f16x4* __restrict__ qw, size_t n4) {
    size_t i = (size_t)blockIdx.x * blockDim.x + threadIdx.x;
    size_t stride = (size_t)gridDim.x * blockDim.x;
    for (; i < n4; i += stride) {
        f32x4 wv = *(const f32x4*)(w + i * 4);
        f32x4 av = *(const f32x4*)(aw + i * 4);
        f16x4 o;
        #pragma unroll
        for (int j = 0; j < 4; ++j) o[j] = (_Float16)quant_interp(wv[j], av[j]);
        qw[i] = o;
    }
}

// ---------------------------------------------------------------------------
// 256x256 NT GEMM, fp16 in / fp32 out. ONE phase / K-tile, ONE barrier / tile.
//   8 waves = 2(M) x 4(N); wave tile 128x64; acc[8][4] f32x4.
//   Key change vs round 3: NO intra-tile barriers and NO manual lgkmcnt(0).
//   ds_reads are issued software-pipelined (bf + af0,af1 preamble; af[mf+2]
//   issued 2 MFMA-groups ahead); the compiler emits COUNTED lgkmcnt waits per
//   MFMA's actual deps, so group-mf MFMAs overlap group-(mf+1/2) LDS reads
//   (separate pipes). Round-3's lockstep [all-read | all-MFMA] serialization
//   (2304 cyc LDS + 2483 cyc MFMA per tile per CU) becomes max(, ) instead.
//   Staging: tile t+1 -> buf^1 issued at tile-t top (WAR-safe: buf^1's old
//   data was fully read by t-1's last lgkm wait + boundary barrier);
//   vmcnt(0) at tile end is ~free (loads issued ~3000 cyc earlier).
//   XOR slot swizzle: phys slot = logical ^ (row&7); inverse applied to the
//   GLOBAL source, linear LDS dest (rule #21). 0 bank conflicts (measured).
// ---------------------------------------------------------------------------
__device__ __forceinline__ void gload_lds16(const void* g, void* l) {
    __builtin_amdgcn_global_load_lds(
        (const __attribute__((address_space(1))) void*)g,
        (__attribute__((address_space(3))) void*)l, 16, 0, 0);
}

__device__ __forceinline__ f16x8 lds_frag(const _Float16* buf, int row, int ks, int hi) {
    const int sl = (ks * 4 + hi) ^ (row & 7);
    return *(const f16x8*)((const char*)buf + row * 128 + sl * 16);
}

__global__ __launch_bounds__(512, 2) void gemm1p_kernel(
    const _Float16* __restrict__ A,   // [M][K] qx
    const _Float16* __restrict__ B,   // [N][K] qw
    const float* __restrict__ bias,   // [N]
    float* __restrict__ C,            // [M][N]
    int M, int N, int K)
{
    constexpr int BK = 64;
    __shared__ _Float16 sA[2][256 * BK];   // 64 KiB
    __shared__ _Float16 sB[2][256 * BK];   // 64 KiB

    const int tid  = (int)threadIdx.x;
    const int lane = tid & 63;
    const int wave = tid >> 6;
    const int wm   = wave >> 2;    // 0..1
    const int wn   = wave & 3;     // 0..3
    const int r15  = lane & 15;
    const int hi   = lane >> 4;

    const int nbx = N >> 8;
    const int nwg = (M >> 8) * nbx;
    const int bid = (int)blockIdx.x;
    const int swz = (nwg & 7) ? bid : ((bid & 7) * (nwg >> 3) + (bid >> 3));
    const size_t bm0 = (size_t)(swz / nbx) << 8;
    const size_t bn0 = (size_t)(swz % nbx) << 8;

    const int nkt = K / BK;
    const _Float16* Agb = A + bm0 * K;
    const _Float16* Bgb = B + bn0 * K;

    // stage one half-tile (128 rows x 64 halfs): which 0=A0 1=A1 2=B0 3=B1
    auto STAGE = [&](int tile, int which) {
        if (tile >= nkt) return;
        const _Float16* g = (which < 2 ? Agb : Bgb) + (size_t)tile * BK;
        _Float16* lb = (which < 2 ? sA[tile & 1] : sB[tile & 1]);
        const int rb = (which & 1) << 7;
        #pragma unroll
        for (int rr = 0; rr < 2; ++rr) {
            const int row = rb + rr * 64 + (tid >> 3);
            const int sg  = (tid & 7) ^ (row & 7);
            gload_lds16(g + (size_t)row * K + sg * 8,
                        (char*)lb + ((rb + rr * 64) << 7) + (wave << 10));
        }
    };

    f32x4 acc[8][4] = {};

    // prologue: stage tile 0 only; drain (once) and sync
    STAGE(0, 0); STAGE(0, 1); STAGE(0, 2); STAGE(0, 3);
    asm volatile("s_waitcnt vmcnt(0)" ::: "memory");
    __builtin_amdgcn_s_barrier();

    for (int t = 0; t < nkt; ++t) {
        const _Float16* Ab = sA[t & 1];
        const _Float16* Bb = sB[t & 1];

        // stage next tile into the other buffer (WAR-safe, see header comment)
        STAGE(t + 1, 0); STAGE(t + 1, 1); STAGE(t + 1, 2); STAGE(t + 1, 3);

        f16x8 af[8][2], bf[4][2];
        // preamble reads: af group 0,1 + all B (register-resident for tile)
        #pragma unroll
        for (int g = 0; g < 2; ++g) {
            const int row = (g >> 2) * 128 + wm * 64 + (g & 3) * 16 + r15;
            af[g][0] = lds_frag(Ab, row, 0, hi);
            af[g][1] = lds_frag(Ab, row, 1, hi);
        }
        #pragma unroll
        for (int nf = 0; nf < 4; ++nf) {
            const int row = (nf >> 1) * 128 + wn * 32 + (nf & 1) * 16 + r15;
            bf[nf][0] = lds_frag(Bb, row, 0, hi);
            bf[nf][1] = lds_frag(Bb, row, 1, hi);
        }

        __builtin_amdgcn_s_setprio(1);
        #pragma unroll
        for (int mf = 0; mf < 8; ++mf) {
            if (mf + 2 < 8) {   // issue reads 2 groups ahead (constant after unroll)
                const int g = mf + 2;
                const int row = (g >> 2) * 128 + wm * 64 + (g & 3) * 16 + r15;
                af[g][0] = lds_frag(Ab, row, 0, hi);
                af[g][1] = lds_frag(Ab, row, 1, hi);
            }
            #pragma unroll
            for (int nf = 0; nf < 4; ++nf) {
                f32x4& ac = acc[mf][nf];
                ac = __builtin_amdgcn_mfma_f32_16x16x32_f16(af[mf][0], bf[nf][0], ac, 0, 0, 0);
                ac = __builtin_amdgcn_mfma_f32_16x16x32_f16(af[mf][1], bf[nf][1], ac, 0, 0, 0);
            }
        }
        __builtin_amdgcn_s_setprio(0);

        // tile boundary: staged loads (issued ~a full tile ago) must be in LDS
        asm volatile("s_waitcnt vmcnt(0)" ::: "memory");
        __builtin_amdgcn_s_barrier();
    }

    // epilogue: C/D layout col = lane&15, row = (lane>>4)*4 + reg
    #pragma unroll
    for (int nf = 0; nf < 4; ++nf) {
        const size_t col = bn0 + (size_t)((nf >> 1) * 128 + wn * 32 + (nf & 1) * 16 + r15);
        const float bv = bias[col];
        #pragma unroll
        for (int mf = 0; mf < 8; ++mf) {
            const size_t row0 = bm0 + (size_t)((mf >> 2) * 128 + wm * 64 + (mf & 3) * 16 + hi * 4);
            #pragma unroll
            for (int r = 0; r < 4; ++r)
                C[(row0 + r) * N + col] = acc[mf][nf][r] + bv;
        }
    }
}

// ---------------------------------------------------------------------------
extern "C" void kernel_launch(void* const* d_in, const int* in_sizes, int n_in,
                              void* d_out, int out_size, void* d_ws, size_t ws_size,
                              hipStream_t stream) {
    const float* x    = (const float*)d_in[0];
    const float* w    = (const float*)d_in[1];
    const float* bias = (const float*)d_in[2];
    const float* aw   = (const float*)d_in[3];
    const float* aA   = (const float*)d_in[4];

    const int    OUT = in_sizes[2];
    const size_t wsz = (size_t)in_sizes[1];
    const int    IN  = (int)(wsz / OUT);
    const int    M   = in_sizes[0] / IN;    // 8192
    const int    N   = OUT;                 // 4096
    const int    K   = IN;                  // 4096

    char* ws = (char*)d_ws;
    _Float16* qx = (_Float16*)ws;                                   // M*K*2
    _Float16* qw = (_Float16*)(ws + (size_t)M * K * 2);             // N*K*2
    float* afeat   = (float*)(ws + (size_t)M * K * 2 + (size_t)N * K * 2);
    float* partial = afeat + K;                                     // 32*K

    const int NCHUNK = 32;
    dim3 g1(K / 256, NCHUNK);
    colsum_partial_kernel<<<g1, 256, 0, stream>>>(aA, partial, K, OUT / NCHUNK);
    colsum_final_kernel<<<K / 256, 256, 0, stream>>>(partial, afeat, K, NCHUNK,
                                                     1.0f / (float)OUT);

    quant_x_kernel<<<2048, 256, 0, stream>>>(x, afeat, (f16x4*)qx, K,
                                             (size_t)M * K / 4);
    quant_w_kernel<<<2048, 256, 0, stream>>>(w, aw, (f16x4*)qw,
                                             (size_t)N * K / 4);

    const int nwg = (M / 256) * (N / 256);
    gemm1p_kernel<<<nwg, 512, 0, stream>>>(qx, qw, bias, (float*)d_out,
                                           M, N, K);
}